// Round 1
// baseline (247.364 us; speedup 1.0000x reference)
//
#include <hip/hip_runtime.h>

// ---------- problem constants ----------
#define M_TOT 16384   // B*S = 32*512
#define N_TOT 4096    // OUT
#define K_TOT 1024    // IN
#define R_LORA 16
#define N_ADAPT 16

#define BM 128
#define BN 128
#define BK 64

typedef __attribute__((ext_vector_type(8))) short bf16x8_t;
typedef __attribute__((ext_vector_type(4))) float f32x4_t;

// RNE float->bf16 (finite inputs only)
__device__ __forceinline__ unsigned short f2bf(float f) {
  unsigned u = __builtin_bit_cast(unsigned, f);
  u += 0x7FFFu + ((u >> 16) & 1u);
  return (unsigned short)(u >> 16);
}

__device__ __forceinline__ void gload_lds16(const void* g, void* l) {
  __builtin_amdgcn_global_load_lds(
      (const __attribute__((address_space(1))) unsigned int*)g,
      (__attribute__((address_space(3))) unsigned int*)l, 16, 0, 0);
}

// ---------- P1: x fp32 -> bf16 (stream) ----------
__global__ __launch_bounds__(256) void conv_x_kernel(const float* __restrict__ x,
                                                     unsigned short* __restrict__ xB) {
  size_t i = (size_t)blockIdx.x * 256 + threadIdx.x;
  const size_t stride = (size_t)gridDim.x * 256;
  const size_t n4 = (size_t)M_TOT * K_TOT / 4;
  for (; i < n4; i += stride) {
    float4 v = ((const float4*)x)[i];
    ushort4 h;
    h.x = f2bf(v.x); h.y = f2bf(v.y); h.z = f2bf(v.z); h.w = f2bf(v.w);
    ((ushort4*)xB)[i] = h;
  }
}

// ---------- P2: Wt[n][k] = bf16(W[k][n]) tiled transpose ----------
__global__ __launch_bounds__(256) void conv_w_kernel(const float* __restrict__ W,
                                                     unsigned short* __restrict__ WtB) {
  __shared__ float lds[64][65];
  const int k0 = blockIdx.x * 64;   // 16 tiles
  const int n0 = blockIdx.y * 64;   // 64 tiles
  const int t = threadIdx.x;
  const int rr = t >> 4;            // 0..15
  const int cc = (t & 15) * 4;      // 0..60
#pragma unroll
  for (int i = 0; i < 4; ++i) {
    int row = i * 16 + rr;
    float4 v = *(const float4*)(W + (size_t)(k0 + row) * N_TOT + n0 + cc);
    lds[row][cc + 0] = v.x; lds[row][cc + 1] = v.y;
    lds[row][cc + 2] = v.z; lds[row][cc + 3] = v.w;
  }
  __syncthreads();
#pragma unroll
  for (int i = 0; i < 4; ++i) {
    int nrow = i * 16 + rr;
    ushort4 h;
    h.x = f2bf(lds[cc + 0][nrow]); h.y = f2bf(lds[cc + 1][nrow]);
    h.z = f2bf(lds[cc + 2][nrow]); h.w = f2bf(lds[cc + 3][nrow]);
    *(ushort4*)(WtB + (size_t)(n0 + nrow) * K_TOT + k0 + cc) = h;
  }
}

// ---------- P3: At[aid][r][k] = bf16(lora_a[aid][k][r]);
//              lbT[aid][n][r] = bf16(SCALING * lora_b[aid][r][n]) ----------
__global__ __launch_bounds__(256) void prep_small_kernel(const float* __restrict__ lora_a,
                                                         const float* __restrict__ lora_b,
                                                         unsigned short* __restrict__ AtB,
                                                         unsigned short* __restrict__ lbT) {
  const int bid = blockIdx.x;
  const int t = threadIdx.x;
  if (bid < 64) {
    // thread per (aid,k): idx in [0, 16*1024)
    int idx = bid * 256 + t;
    int aid = idx >> 10;
    int k = idx & 1023;
    const float* src = lora_a + (size_t)idx * 16;
#pragma unroll
    for (int q = 0; q < 4; ++q) {
      float4 v = ((const float4*)src)[q];
#pragma unroll
      for (int j = 0; j < 4; ++j) {
        int r = q * 4 + j;
        float val = (j == 0) ? v.x : (j == 1) ? v.y : (j == 2) ? v.z : v.w;
        AtB[(((size_t)aid * 16 + r) << 10) + k] = f2bf(val);
      }
    }
  } else {
    // thread per (aid,n): idx in [0, 16*4096)
    int idx = (bid - 64) * 256 + t;
    int aid = idx >> 12;
    int n = idx & 4095;
    unsigned short o[16];
#pragma unroll
    for (int r = 0; r < 16; ++r)
      o[r] = f2bf(lora_b[((size_t)aid * 16 + r) * N_TOT + n] * 1.0f /* SCALING=16/16 */);
    ushort4* dst = (ushort4*)(lbT + ((size_t)aid * N_TOT + n) * 16);
#pragma unroll
    for (int q = 0; q < 4; ++q) {
      ushort4 h; h.x = o[q*4+0]; h.y = o[q*4+1]; h.z = o[q*4+2]; h.w = o[q*4+3];
      dst[q] = h;
    }
  }
}

// ---------- P4: low_rank[m][r] = bf16( sum_k x[m][k]*A[aid][k][r] ) via MFMA ----------
__global__ __launch_bounds__(256) void lowrank_kernel(const unsigned short* __restrict__ xB,
                                                      const unsigned short* __restrict__ AtB,
                                                      const int* __restrict__ aids,
                                                      unsigned short* __restrict__ lrB) {
  __shared__ char As[BM * BK * 2];  // 16 KB
  const int blk = blockIdx.x;       // 0..127
  const int t = threadIdx.x;
  const int lane = t & 63;
  const int w = t >> 6;
  const int fr = lane & 15, fq = lane >> 4;
  const int aid = aids[blk >> 2];   // 128-row tile within one sample

  const unsigned short* aSrc[4];
  char* aDst[4];
#pragma unroll
  for (int r = 0; r < 4; ++r) {
    int off = (r * 256 + t) * 16;
    int row = off >> 7, cb = off & 127;
    int sb = cb ^ ((row & 7) << 4);        // inverse swizzle on SOURCE
    aSrc[r] = xB + (size_t)(blk * BM + row) * K_TOT + (sb >> 1);
    aDst[r] = As + off;                    // linear LDS dest
  }
  const unsigned short* bBase = AtB + ((size_t)aid * 16 + fr) * K_TOT + fq * 8;

  f32x4_t acc[2];
  acc[0] = (f32x4_t){0.f, 0.f, 0.f, 0.f};
  acc[1] = (f32x4_t){0.f, 0.f, 0.f, 0.f};

  for (int kt = 0; kt < K_TOT / BK; ++kt) {
#pragma unroll
    for (int r = 0; r < 4; ++r) gload_lds16(aSrc[r] + kt * BK, aDst[r]);
    __syncthreads();
#pragma unroll
    for (int ks = 0; ks < 2; ++ks) {
      bf16x8_t bfr = *(const bf16x8_t*)(bBase + kt * BK + ks * 32);
#pragma unroll
      for (int m = 0; m < 2; ++m) {
        int row = w * 32 + m * 16 + fr;
        int cb = ks * 64 + fq * 16;
        bf16x8_t af = *(const bf16x8_t*)(As + row * 128 + (cb ^ ((row & 7) << 4)));
        acc[m] = __builtin_amdgcn_mfma_f32_16x16x32_bf16(af, bfr, acc[m], 0, 0, 0);
      }
    }
    __syncthreads();
  }
#pragma unroll
  for (int m = 0; m < 2; ++m) {
    int gm0 = blk * BM + w * 32 + m * 16 + fq * 4;
#pragma unroll
    for (int q = 0; q < 4; ++q)
      lrB[(size_t)(gm0 + q) * R_LORA + fr] = f2bf(acc[m][q]);
  }
}

// ---------- main GEMM: out = xB @ WtB^T + bias + lr @ lbT^T ----------
__global__ __launch_bounds__(256) void gemm_kernel(const unsigned short* __restrict__ xB,
                                                   const unsigned short* __restrict__ WtB,
                                                   const unsigned short* __restrict__ lrB,
                                                   const unsigned short* __restrict__ lbT,
                                                   const float* __restrict__ bias,
                                                   const int* __restrict__ aids,
                                                   float* __restrict__ out) {
  __shared__ char smem[2 * BM * BK * 2];  // As 16K + Bs 16K
  char* As = smem;
  char* Bs = smem + BM * BK * 2;

  // XCD-aware bijective swizzle (4096 % 8 == 0)
  const int orig = blockIdx.x;
  const int wg = (orig & 7) * (4096 / 8) + (orig >> 3);
  const int tn = wg & 31;   // N_TOT/BN = 32
  const int tm = wg >> 5;   // M_TOT/BM = 128

  const int t = threadIdx.x;
  const int lane = t & 63;
  const int w = t >> 6;
  const int wr = w >> 1, wc = w & 1;
  const int fr = lane & 15, fq = lane >> 4;

  const unsigned short* aSrc[4];
  const unsigned short* bSrc[4];
  char* aDst[4];
  char* bDst[4];
#pragma unroll
  for (int r = 0; r < 4; ++r) {
    int off = (r * 256 + t) * 16;
    int row = off >> 7, cb = off & 127;
    int sb = cb ^ ((row & 7) << 4);        // inverse swizzle on SOURCE
    aSrc[r] = xB + (size_t)(tm * BM + row) * K_TOT + (sb >> 1);
    bSrc[r] = WtB + (size_t)(tn * BN + row) * K_TOT + (sb >> 1);
    aDst[r] = As + off;
    bDst[r] = Bs + off;
  }

  f32x4_t acc[4][4];
#pragma unroll
  for (int m = 0; m < 4; ++m)
#pragma unroll
    for (int n = 0; n < 4; ++n) acc[m][n] = (f32x4_t){0.f, 0.f, 0.f, 0.f};

  for (int kt = 0; kt < K_TOT / BK; ++kt) {
#pragma unroll
    for (int r = 0; r < 4; ++r) gload_lds16(aSrc[r] + kt * BK, aDst[r]);
#pragma unroll
    for (int r = 0; r < 4; ++r) gload_lds16(bSrc[r] + kt * BK, bDst[r]);
    __syncthreads();   // drains vmcnt(0) then barrier
#pragma unroll
    for (int ks = 0; ks < 2; ++ks) {
      bf16x8_t af[4], bf[4];
#pragma unroll
      for (int m = 0; m < 4; ++m) {
        int row = wr * 64 + m * 16 + fr;
        int cb = ks * 64 + fq * 16;
        af[m] = *(const bf16x8_t*)(As + row * 128 + (cb ^ ((row & 7) << 4)));
      }
#pragma unroll
      for (int n = 0; n < 4; ++n) {
        int row = wc * 64 + n * 16 + fr;
        int cb = ks * 64 + fq * 16;
        bf[n] = *(const bf16x8_t*)(Bs + row * 128 + (cb ^ ((row & 7) << 4)));
      }
#pragma unroll
      for (int m = 0; m < 4; ++m)
#pragma unroll
        for (int n = 0; n < 4; ++n)
          acc[m][n] = __builtin_amdgcn_mfma_f32_16x16x32_bf16(af[m], bf[n], acc[m][n], 0, 0, 0);
    }
    __syncthreads();
  }

  // ---- LoRA epilogue: one extra MFMA per acc (K padded 16->32 with zero lanes) ----
  const int aid = aids[tm >> 2];
  bf16x8_t z8 = {0, 0, 0, 0, 0, 0, 0, 0};
  bf16x8_t lrf[4], lbf[4];
#pragma unroll
  for (int m = 0; m < 4; ++m) { lrf[m] = z8; lbf[m] = z8; }
  if (fq < 2) {  // k = fq*8 + i < 16
#pragma unroll
    for (int m = 0; m < 4; ++m)
      lrf[m] = *(const bf16x8_t*)(lrB + (size_t)(tm * BM + wr * 64 + m * 16 + fr) * R_LORA + fq * 8);
#pragma unroll
    for (int n = 0; n < 4; ++n)
      lbf[n] = *(const bf16x8_t*)(lbT + ((size_t)aid * N_TOT + tn * BN + wc * 64 + n * 16 + fr) * R_LORA + fq * 8);
  }
#pragma unroll
  for (int m = 0; m < 4; ++m)
#pragma unroll
    for (int n = 0; n < 4; ++n)
      acc[m][n] = __builtin_amdgcn_mfma_f32_16x16x32_bf16(lrf[m], lbf[n], acc[m][n], 0, 0, 0);

  // ---- bias + store (C/D layout: col=lane&15, row=(lane>>4)*4+reg) ----
#pragma unroll
  for (int n = 0; n < 4; ++n) {
    int gn = tn * BN + wc * 64 + n * 16 + fr;
    float bv = bias[gn];
#pragma unroll
    for (int m = 0; m < 4; ++m) {
      int gm0 = tm * BM + wr * 64 + m * 16 + fq * 4;
      float* op = out + (size_t)gm0 * N_TOT + gn;
#pragma unroll
      for (int q = 0; q < 4; ++q) op[(size_t)q * N_TOT] = acc[m][n][q] + bv;
    }
  }
}

extern "C" void kernel_launch(void* const* d_in, const int* in_sizes, int n_in,
                              void* d_out, int out_size, void* d_ws, size_t ws_size,
                              hipStream_t stream) {
  const float* x      = (const float*)d_in[0];
  const int*   aids   = (const int*)d_in[1];
  const float* W      = (const float*)d_in[2];
  const float* bias   = (const float*)d_in[3];
  const float* lora_a = (const float*)d_in[4];
  const float* lora_b = (const float*)d_in[5];
  float* out = (float*)d_out;

  char* ws = (char*)d_ws;
  unsigned short* xB  = (unsigned short*)(ws);                                  // 32 MB
  unsigned short* WtB = (unsigned short*)(ws + (size_t)32 * 1024 * 1024);       //  8 MB
  unsigned short* lrB = (unsigned short*)(ws + (size_t)40 * 1024 * 1024);       // 512 KB
  unsigned short* AtB = (unsigned short*)(ws + (size_t)40 * 1024 * 1024 + 512 * 1024); // 512 KB
  unsigned short* lbT = (unsigned short*)(ws + (size_t)41 * 1024 * 1024);       //  2 MB

  conv_x_kernel<<<2048, 256, 0, stream>>>(x, xB);
  conv_w_kernel<<<dim3(16, 64), 256, 0, stream>>>(W, WtB);
  prep_small_kernel<<<320, 256, 0, stream>>>(lora_a, lora_b, AtB, lbT);
  lowrank_kernel<<<128, 256, 0, stream>>>(xB, AtB, aids, lrB);
  gemm_kernel<<<4096, 256, 0, stream>>>(xB, WtB, lrB, lbT, bias, aids, out);
}

// Round 2
// 213.344 us; speedup vs baseline: 1.1595x; 1.1595x over previous
//
#include <hip/hip_runtime.h>

// ---------- problem constants ----------
#define M_TOT 16384   // B*S = 32*512
#define N_TOT 4096    // OUT
#define K_TOT 1024    // IN
#define R_LORA 16

// ---------- 256x256 8-phase GEMM geometry ----------
#define BM 256
#define BN 256
#define BK 64
#define NT (K_TOT / BK)   // 16 K-tiles

typedef __attribute__((ext_vector_type(8))) short bf16x8_t;
typedef __attribute__((ext_vector_type(4))) float f32x4_t;

// RNE float->bf16 (finite inputs only)
__device__ __forceinline__ unsigned short f2bf(float f) {
  unsigned u = __builtin_bit_cast(unsigned, f);
  u += 0x7FFFu + ((u >> 16) & 1u);
  return (unsigned short)(u >> 16);
}

__device__ __forceinline__ void gload_lds16(const void* g, void* l) {
  __builtin_amdgcn_global_load_lds(
      (const __attribute__((address_space(1))) unsigned int*)g,
      (__attribute__((address_space(3))) unsigned int*)l, 16, 0, 0);
}

// ---------- fused prep: x->bf16, W->Wt bf16, lora_a/b repack ----------
__global__ __launch_bounds__(256) void prep_kernel(const float* __restrict__ x,
                                                   const float* __restrict__ W,
                                                   const float* __restrict__ lora_a,
                                                   const float* __restrict__ lora_b,
                                                   unsigned short* __restrict__ xB,
                                                   unsigned short* __restrict__ WtB,
                                                   unsigned short* __restrict__ AtB,
                                                   unsigned short* __restrict__ lbT) {
  __shared__ float lds[64][65];
  const int bid = blockIdx.x;
  const int t = threadIdx.x;
  if (bid < 1024) {
    // ---- x fp32 -> bf16 stream ----
    size_t i = (size_t)bid * 256 + t;
    const size_t stride = (size_t)1024 * 256;
    const size_t n4 = (size_t)M_TOT * K_TOT / 4;
    for (; i < n4; i += stride) {
      float4 v = ((const float4*)x)[i];
      ushort4 h;
      h.x = f2bf(v.x); h.y = f2bf(v.y); h.z = f2bf(v.z); h.w = f2bf(v.w);
      ((ushort4*)xB)[i] = h;
    }
  } else if (bid < 2048) {
    // ---- Wt[n][k] = bf16(W[k][n]) tiled transpose ----
    const int v = bid - 1024;
    const int k0 = (v & 15) * 64;
    const int n0 = (v >> 4) * 64;
    const int rr = t >> 4;
    const int cc = (t & 15) * 4;
#pragma unroll
    for (int i = 0; i < 4; ++i) {
      int row = i * 16 + rr;
      float4 w4 = *(const float4*)(W + (size_t)(k0 + row) * N_TOT + n0 + cc);
      lds[row][cc + 0] = w4.x; lds[row][cc + 1] = w4.y;
      lds[row][cc + 2] = w4.z; lds[row][cc + 3] = w4.w;
    }
    __syncthreads();
#pragma unroll
    for (int i = 0; i < 4; ++i) {
      int nrow = i * 16 + rr;
      ushort4 h;
      h.x = f2bf(lds[cc + 0][nrow]); h.y = f2bf(lds[cc + 1][nrow]);
      h.z = f2bf(lds[cc + 2][nrow]); h.w = f2bf(lds[cc + 3][nrow]);
      *(ushort4*)(WtB + (size_t)(n0 + nrow) * K_TOT + k0 + cc) = h;
    }
  } else {
    const int b2 = bid - 2048;  // 0..319
    if (b2 < 64) {
      // At[aid][r][k] = bf16(lora_a[aid][k][r])
      int idx = b2 * 256 + t;
      int aid = idx >> 10;
      int k = idx & 1023;
      const float* src = lora_a + (size_t)idx * 16;
#pragma unroll
      for (int q = 0; q < 4; ++q) {
        float4 v4 = ((const float4*)src)[q];
#pragma unroll
        for (int j = 0; j < 4; ++j) {
          int r = q * 4 + j;
          float val = (j == 0) ? v4.x : (j == 1) ? v4.y : (j == 2) ? v4.z : v4.w;
          AtB[(((size_t)aid * 16 + r) << 10) + k] = f2bf(val);
        }
      }
    } else {
      // lbT[aid][n][r] = bf16(lora_b[aid][r][n])  (SCALING = 16/16 = 1)
      int idx = (b2 - 64) * 256 + t;
      int aid = idx >> 12;
      int n = idx & 4095;
      unsigned short o[16];
#pragma unroll
      for (int r = 0; r < 16; ++r)
        o[r] = f2bf(lora_b[((size_t)aid * 16 + r) * N_TOT + n]);
      ushort4* dst = (ushort4*)(lbT + ((size_t)aid * N_TOT + n) * 16);
#pragma unroll
      for (int q = 0; q < 4; ++q) {
        ushort4 h; h.x = o[q*4+0]; h.y = o[q*4+1]; h.z = o[q*4+2]; h.w = o[q*4+3];
        dst[q] = h;
      }
    }
  }
}

// ---------- low_rank[m][r] = bf16( sum_k x[m][k]*A[aid][k][r] ) ----------
__global__ __launch_bounds__(256) void lowrank_kernel(const unsigned short* __restrict__ xB,
                                                      const unsigned short* __restrict__ AtB,
                                                      const int* __restrict__ aids,
                                                      unsigned short* __restrict__ lrB) {
  __shared__ char As[128 * 128];  // 16 KB: 128 rows x 64 bf16
  const int blk = blockIdx.x;     // 0..127
  const int t = threadIdx.x;
  const int lane = t & 63;
  const int w = t >> 6;
  const int fr = lane & 15, fq = lane >> 4;
  const int aid = aids[blk >> 2];

  const unsigned short* aSrc[4];
  char* aDst[4];
#pragma unroll
  for (int r = 0; r < 4; ++r) {
    int off = (r * 256 + t) * 16;
    int row = off >> 7, cb = off & 127;
    int sb = cb ^ ((row & 7) << 4);
    aSrc[r] = xB + (size_t)(blk * 128 + row) * K_TOT + (sb >> 1);
    aDst[r] = As + off;
  }
  const unsigned short* bBase = AtB + ((size_t)aid * 16 + fr) * K_TOT + fq * 8;

  f32x4_t acc[2];
  acc[0] = (f32x4_t){0.f, 0.f, 0.f, 0.f};
  acc[1] = (f32x4_t){0.f, 0.f, 0.f, 0.f};

  for (int kt = 0; kt < K_TOT / 64; ++kt) {
#pragma unroll
    for (int r = 0; r < 4; ++r) gload_lds16(aSrc[r] + kt * 64, aDst[r]);
    __syncthreads();
#pragma unroll
    for (int ks = 0; ks < 2; ++ks) {
      bf16x8_t bfr = *(const bf16x8_t*)(bBase + kt * 64 + ks * 32);
#pragma unroll
      for (int m = 0; m < 2; ++m) {
        int row = w * 32 + m * 16 + fr;
        int cb = ks * 64 + fq * 16;
        bf16x8_t af = *(const bf16x8_t*)(As + row * 128 + (cb ^ ((row & 7) << 4)));
        acc[m] = __builtin_amdgcn_mfma_f32_16x16x32_bf16(af, bfr, acc[m], 0, 0, 0);
      }
    }
    __syncthreads();
  }
#pragma unroll
  for (int m = 0; m < 2; ++m) {
    int gm0 = blk * 128 + w * 32 + m * 16 + fq * 4;
#pragma unroll
    for (int q = 0; q < 4; ++q)
      lrB[(size_t)(gm0 + q) * R_LORA + fr] = f2bf(acc[m][q]);
  }
}

// ---------- main GEMM: 256x256 tile, 8 waves, 8-phase counted-vmcnt ----------
#define BAR() __builtin_amdgcn_s_barrier()
#define WAIT_LGKM0() asm volatile("s_waitcnt lgkmcnt(0)" ::: "memory")

#define STAGE_HALF(gbase, koff, ldsbase)                                   \
  do {                                                                     \
    gload_lds16((const char*)(gbase) + (koff), (ldsbase) + t * 16);        \
    gload_lds16((const char*)(gbase) + 64 * 2048 + (koff),                 \
                (ldsbase) + 8192 + t * 16);                                \
  } while (0)

// A-frags for quadrant MH into aF (4 m x 2 ks)
#define LDA(MH)                                                            \
  do {                                                                     \
    _Pragma("unroll") for (int m = 0; m < 4; ++m)                          \
      _Pragma("unroll") for (int ks = 0; ks < 2; ++ks)                     \
        aF[m][ks] = *(const bf16x8_t*)(bufA + (MH) * 8192 + m * 2048 +     \
                                       (laneA ^ (ks << 6)));               \
  } while (0)

// B-frags for n-half NH (2 n x 2 ks)
#define LDB(NH)                                                            \
  do {                                                                     \
    _Pragma("unroll") for (int n = 0; n < 2; ++n)                          \
      _Pragma("unroll") for (int ks = 0; ks < 2; ++ks)                     \
        bF[NH][n][ks] = *(const bf16x8_t*)(bufB + (NH) * 4096 + n * 2048 + \
                                           (laneA ^ (ks << 6)));           \
  } while (0)

#define MM(MH, NH)                                                         \
  do {                                                                     \
    __builtin_amdgcn_s_setprio(1);                                         \
    _Pragma("unroll") for (int ks = 0; ks < 2; ++ks)                       \
      _Pragma("unroll") for (int m = 0; m < 4; ++m)                        \
        _Pragma("unroll") for (int n = 0; n < 2; ++n)                      \
          acc[(MH) * 4 + m][(NH) * 2 + n] =                                \
              __builtin_amdgcn_mfma_f32_16x16x32_bf16(                     \
                  aF[m][ks], bF[NH][n][ks],                                \
                  acc[(MH) * 4 + m][(NH) * 2 + n], 0, 0, 0);               \
    __builtin_amdgcn_s_setprio(0);                                         \
  } while (0)

__global__ __launch_bounds__(512, 1) void gemm_kernel(
    const unsigned short* __restrict__ xB, const unsigned short* __restrict__ WtB,
    const unsigned short* __restrict__ lrB, const unsigned short* __restrict__ lbT,
    const float* __restrict__ bias, const int* __restrict__ aids,
    float* __restrict__ out) {
  // LDS: 2 buffers x { A0 | A1 | B0 | B1 } x 16 KB = 128 KB
  __shared__ char smem[131072];

  // XCD-aware bijective swizzle (1024 % 8 == 0)
  const int orig = blockIdx.x;
  const int wg = (orig & 7) * 128 + (orig >> 3);
  const int tn = wg & 15;   // N_TOT/BN = 16
  const int tm = wg >> 4;   // M_TOT/BM = 64

  const int t = threadIdx.x;
  const int lane = t & 63;
  const int wid = t >> 6;
  const int wr = wid >> 2;        // 0..1 : A half / row band
  const int wc = wid & 3;         // 0..3 : 64-col band
  const int fr = lane & 15, fq = lane >> 4;

  // per-lane swizzled LDS fragment offset: row=fr, col byte = fq*16, ks flips bit6
  const int laneA = fr * 128 + (((fq << 4) ^ ((fr & 7) << 4)));
  const int waveAoff = wr * 16384;
  const int waveBoff = 32768 + (wc >> 1) * 16384 + (wc & 1) * 8192;

  // staging source pointers (pre-swizzled byte-in-row)
  const int srow = t >> 3;
  const int sb = (((t & 7) ^ (srow & 7)) << 4);
  const char* pAsrc0 = (const char*)xB + (size_t)(tm * 256 + srow) * 2048 + sb;
  const char* pAsrc1 = pAsrc0 + (size_t)128 * 2048;
  const char* pBsrc0 = (const char*)WtB + (size_t)(tn * 256 + srow) * 2048 + sb;
  const char* pBsrc1 = pBsrc0 + (size_t)128 * 2048;

  f32x4_t acc[8][4];
#pragma unroll
  for (int m = 0; m < 8; ++m)
#pragma unroll
    for (int n = 0; n < 4; ++n) acc[m][n] = (f32x4_t){0.f, 0.f, 0.f, 0.f};

  bf16x8_t aF[4][2];
  bf16x8_t bF[2][2][2];

  // ---- prologue: fill kt=0 fully + B(1); A(1) staged in-loop at P0/P1(0) ----
  STAGE_HALF(pAsrc0, 0, smem + 0);
  STAGE_HALF(pAsrc1, 0, smem + 16384);
  STAGE_HALF(pBsrc0, 0, smem + 32768);
  STAGE_HALF(pBsrc1, 0, smem + 49152);
  STAGE_HALF(pBsrc0, 128, smem + 65536 + 32768);
  STAGE_HALF(pBsrc1, 128, smem + 65536 + 49152);
  asm volatile("s_waitcnt vmcnt(4)" ::: "memory");
  BAR();

#pragma unroll 1
  for (int kt = 0; kt < NT; ++kt) {
    char* base = smem + ((kt & 1) << 16);
    char* nbase = smem + (((kt + 1) & 1) << 16);
    char* bufA = base + waveAoff;
    char* bufB = base + waveBoff;
    const int kb1 = (kt + 1) * 128;
    const int kb2 = (kt + 2) * 128;

    // P0: quadrant (mh0, nh0); stage A0(kt+1)
    LDA(0);
    LDB(0);
    if (kt + 1 < NT) STAGE_HALF(pAsrc0, kb1, nbase + 0);
    asm volatile("s_waitcnt lgkmcnt(8)" ::: "memory");
    BAR(); WAIT_LGKM0();
    MM(0, 0);
    BAR();

    // P1: quadrant (mh0, nh1); stage A1(kt+1)
    LDB(1);
    if (kt + 1 < NT) STAGE_HALF(pAsrc1, kb1, nbase + 16384);
    BAR(); WAIT_LGKM0();
    MM(0, 1);
    BAR();

    // P2: quadrant (mh1, nh1); stage B0(kt+2)
    LDA(1);
    if (kt + 2 < NT) STAGE_HALF(pBsrc0, kb2, base + 32768);
    BAR(); WAIT_LGKM0();
    MM(1, 1);
    BAR();

    // P3: quadrant (mh1, nh0); stage B1(kt+2); counted vmcnt per K-tile
    if (kt + 2 < NT) STAGE_HALF(pBsrc1, kb2, base + 49152);
    BAR(); WAIT_LGKM0();
    MM(1, 0);
    if (kt < NT - 2) asm volatile("s_waitcnt vmcnt(4)" ::: "memory");
    else             asm volatile("s_waitcnt vmcnt(0)" ::: "memory");
    BAR();
  }

  // ---- LoRA epilogue: one extra MFMA per acc (K padded 16->32) ----
  const int aid = aids[tm >> 1];  // 256 rows = half a sample (S=512)
  bf16x8_t z8 = (bf16x8_t){0, 0, 0, 0, 0, 0, 0, 0};
  bf16x8_t lrf[8], lbf[4];
#pragma unroll
  for (int m = 0; m < 8; ++m) lrf[m] = z8;
#pragma unroll
  for (int n = 0; n < 4; ++n) lbf[n] = z8;
  if (fq < 2) {
#pragma unroll
    for (int m = 0; m < 8; ++m)
      lrf[m] = *(const bf16x8_t*)(lrB + (size_t)(tm * 256 + wr * 128 + m * 16 + fr) * R_LORA + fq * 8);
#pragma unroll
    for (int n = 0; n < 4; ++n)
      lbf[n] = *(const bf16x8_t*)(lbT + ((size_t)aid * N_TOT + tn * 256 + wc * 64 + n * 16 + fr) * R_LORA + fq * 8);
  }
#pragma unroll
  for (int m = 0; m < 8; ++m)
#pragma unroll
    for (int n = 0; n < 4; ++n)
      acc[m][n] = __builtin_amdgcn_mfma_f32_16x16x32_bf16(lrf[m], lbf[n], acc[m][n], 0, 0, 0);

  // ---- bias + store (C/D: col=lane&15, row=(lane>>4)*4+q) ----
#pragma unroll
  for (int n = 0; n < 4; ++n) {
    int gn = tn * 256 + wc * 64 + n * 16 + fr;
    float bv = bias[gn];
#pragma unroll
    for (int m = 0; m < 8; ++m) {
      int gm0 = tm * 256 + wr * 128 + m * 16 + fq * 4;
      float* op = out + (size_t)gm0 * N_TOT + gn;
#pragma unroll
      for (int q = 0; q < 4; ++q) op[(size_t)q * N_TOT] = acc[m][n][q] + bv;
    }
  }
}

extern "C" void kernel_launch(void* const* d_in, const int* in_sizes, int n_in,
                              void* d_out, int out_size, void* d_ws, size_t ws_size,
                              hipStream_t stream) {
  const float* x      = (const float*)d_in[0];
  const int*   aids   = (const int*)d_in[1];
  const float* W      = (const float*)d_in[2];
  const float* bias   = (const float*)d_in[3];
  const float* lora_a = (const float*)d_in[4];
  const float* lora_b = (const float*)d_in[5];
  float* out = (float*)d_out;

  char* ws = (char*)d_ws;
  unsigned short* xB  = (unsigned short*)(ws);                                   // 32 MB
  unsigned short* WtB = (unsigned short*)(ws + (size_t)32 * 1024 * 1024);        //  8 MB
  unsigned short* lrB = (unsigned short*)(ws + (size_t)40 * 1024 * 1024);        // 512 KB
  unsigned short* AtB = (unsigned short*)(ws + (size_t)40 * 1024 * 1024 + 512 * 1024); // 512 KB
  unsigned short* lbT = (unsigned short*)(ws + (size_t)41 * 1024 * 1024);        //  2 MB

  prep_kernel<<<2368, 256, 0, stream>>>(x, W, lora_a, lora_b, xB, WtB, AtB, lbT);
  lowrank_kernel<<<128, 256, 0, stream>>>(xB, AtB, aids, lrB);
  gemm_kernel<<<1024, 512, 0, stream>>>(xB, WtB, lrB, lbT, bias, aids, out);
}